// Round 1
// baseline (752.756 us; speedup 1.0000x reference)
//
#include <hip/hip_runtime.h>
#include <math.h>

#define BB 32
#define TT_TOTAL 4096
#define DD 512
#define UU 256

// score kernel tiling
#define TTILE 64   // t rows per block
#define BK 64      // k (d) chunk
#define LDA 68     // padded LDS row stride (floats): 68*4=272 B, 16B aligned, breaks pow2 banks

// context kernel tiling
#define TC 256     // t rows per context block

// ---------------------------------------------------------------------------
// Kernel 1: h_query[b,u] = sum_d query[b,d] * W2[d,u] + b2[u]
__global__ __launch_bounds__(256) void hquery_kernel(
    const float* __restrict__ query, const float* __restrict__ W2,
    const float* __restrict__ b2, float* __restrict__ hq) {
  const int b = blockIdx.x;
  const int u = threadIdx.x;  // 0..255
  __shared__ float q[DD];
  for (int d = threadIdx.x; d < DD; d += 256) q[d] = query[b * DD + d];
  __syncthreads();
  float acc = b2[u];
  for (int d = 0; d < DD; ++d) acc += q[d] * W2[d * UU + u];
  hq[b * UU + u] = acc;
}

// ---------------------------------------------------------------------------
// Kernel 2: scores[b,t] = sum_u tanh( (values[b,t,:] @ W1[:,u]) + b1[u] + hq[b,u] ) * V[u] + bV
// Block tile: 64 t x 256 u, 256 threads, each thread 8t x 8u micro-tile.
__global__ __launch_bounds__(256) void score_kernel(
    const float* __restrict__ values, const float* __restrict__ W1,
    const float* __restrict__ b1, const float* __restrict__ hq,
    const float* __restrict__ V, const float* __restrict__ bV,
    float* __restrict__ scores) {
  const int b  = blockIdx.y;
  const int t0 = blockIdx.x * TTILE;
  const int tid = threadIdx.x;
  const int tu = tid & 31;   // u-group: owns u0..u0+7
  const int tt = tid >> 5;   // t-group: owns rows tt*8..tt*8+7
  const int u0 = tu * 8;

  __shared__ float As[TTILE][LDA];      // As[t][k], natural layout, padded
  __shared__ float red[TTILE][33];      // epilogue reduction

  float acc[8][8];
#pragma unroll
  for (int i = 0; i < 8; ++i)
#pragma unroll
    for (int j = 0; j < 8; ++j) acc[i][j] = 0.0f;

  const size_t vbase = ((size_t)b * TT_TOTAL + t0) * DD;

  for (int d0 = 0; d0 < DD; d0 += BK) {
    __syncthreads();  // protect previous-iteration reads
    // stage 64 rows x 64 k floats: 1024 float4s, 4 per thread
#pragma unroll
    for (int it = 0; it < 4; ++it) {
      const int idx = it * 256 + tid;
      const int r = idx >> 4;        // 0..63
      const int c4 = idx & 15;       // 0..15 (float4 index within BK)
      const float4 g = *(const float4*)&values[vbase + (size_t)r * DD + d0 + c4 * 4];
      *(float4*)&As[r][c4 * 4] = g;
    }
    __syncthreads();

#pragma unroll 4
    for (int k = 0; k < BK; ++k) {
      const float4 w0 = *(const float4*)&W1[(d0 + k) * UU + u0];
      const float4 w1 = *(const float4*)&W1[(d0 + k) * UU + u0 + 4];
      float w[8] = {w0.x, w0.y, w0.z, w0.w, w1.x, w1.y, w1.z, w1.w};
#pragma unroll
      for (int i = 0; i < 8; ++i) {
        const float a = As[tt * 8 + i][k];
#pragma unroll
        for (int j = 0; j < 8; ++j) acc[i][j] += a * w[j];
      }
    }
  }

  // epilogue: + b1 + hq, tanh, * V, partial-sum over this thread's 8 u's
  float bias[8], hqr[8], vv[8];
#pragma unroll
  for (int j = 0; j < 8; ++j) {
    bias[j] = b1[u0 + j];
    hqr[j] = hq[b * UU + u0 + j];
    vv[j] = V[u0 + j];
  }
  float part[8];
#pragma unroll
  for (int i = 0; i < 8; ++i) {
    float s = 0.0f;
#pragma unroll
    for (int j = 0; j < 8; ++j) {
      const float h = acc[i][j] + bias[j] + hqr[j];
      s += tanhf(h) * vv[j];
    }
    part[i] = s;
  }

  __syncthreads();
#pragma unroll
  for (int i = 0; i < 8; ++i) red[tt * 8 + i][tu] = part[i];
  __syncthreads();

  if (tid < TTILE) {
    float s = bV[0];
#pragma unroll
    for (int x = 0; x < 32; ++x) s += red[tid][x];
    scores[b * TT_TOTAL + t0 + tid] = s;
  }
}

// ---------------------------------------------------------------------------
// Kernel 3: per-b softmax stats (max m, sum l of exp(s-m)) over T
__global__ __launch_bounds__(256) void softmax_stats_kernel(
    const float* __restrict__ scores, float* __restrict__ stats) {
  const int b = blockIdx.x;
  const int tid = threadIdx.x;
  __shared__ float sm[256];
  float m = -1e30f;
  for (int t = tid; t < TT_TOTAL; t += 256) m = fmaxf(m, scores[b * TT_TOTAL + t]);
  sm[tid] = m;
  __syncthreads();
  for (int s = 128; s > 0; s >>= 1) {
    if (tid < s) sm[tid] = fmaxf(sm[tid], sm[tid + s]);
    __syncthreads();
  }
  m = sm[0];
  __syncthreads();
  float l = 0.0f;
  for (int t = tid; t < TT_TOTAL; t += 256) l += __expf(scores[b * TT_TOTAL + t] - m);
  sm[tid] = l;
  __syncthreads();
  for (int s = 128; s > 0; s >>= 1) {
    if (tid < s) sm[tid] += sm[tid + s];
    __syncthreads();
  }
  if (tid == 0) {
    stats[2 * b] = m;
    stats[2 * b + 1] = sm[0];
  }
}

// ---------------------------------------------------------------------------
// Kernel 4: weights out + context partial sums (atomicAdd into zeroed region)
__global__ __launch_bounds__(256) void context_kernel(
    const float* __restrict__ values, const float* __restrict__ scores,
    const float* __restrict__ stats, float* __restrict__ out) {
  const int b = blockIdx.y;
  const int tc0 = blockIdx.x * TC;
  const int tid = threadIdx.x;
  const float m = stats[2 * b];
  const float linv = 1.0f / stats[2 * b + 1];

  __shared__ float wts[TC];
  for (int t = tid; t < TC; t += 256) {
    const float w = __expf(scores[b * TT_TOTAL + tc0 + t] - m) * linv;
    wts[t] = w;
    out[BB * DD + b * TT_TOTAL + tc0 + t] = w;  // attention_weights output
  }
  __syncthreads();

  const float2* __restrict__ vp =
      (const float2*)(values + ((size_t)b * TT_TOTAL + tc0) * DD);
  float accx = 0.0f, accy = 0.0f;
#pragma unroll 4
  for (int t = 0; t < TC; ++t) {
    const float w = wts[t];
    const float2 v2 = vp[(size_t)t * (DD / 2) + tid];
    accx += w * v2.x;
    accy += w * v2.y;
  }
  atomicAdd(&out[b * DD + 2 * tid], accx);
  atomicAdd(&out[b * DD + 2 * tid + 1], accy);
}

// ---------------------------------------------------------------------------
extern "C" void kernel_launch(void* const* d_in, const int* in_sizes, int n_in,
                              void* d_out, int out_size, void* d_ws, size_t ws_size,
                              hipStream_t stream) {
  const float* values = (const float*)d_in[0];
  const float* query  = (const float*)d_in[1];
  const float* W1     = (const float*)d_in[2];
  const float* b1     = (const float*)d_in[3];
  const float* W2     = (const float*)d_in[4];
  const float* b2     = (const float*)d_in[5];
  const float* V      = (const float*)d_in[6];
  const float* bV     = (const float*)d_in[7];
  float* out = (float*)d_out;

  float* ws = (float*)d_ws;
  float* hq     = ws;                      // B*U      = 8192 floats
  float* scores = ws + BB * UU;            // B*T      = 131072 floats
  float* stats  = scores + BB * TT_TOTAL;  // 2*B      = 64 floats

  // zero the context accumulation region (harness poisons d_out with 0xAA)
  hipMemsetAsync(out, 0, BB * DD * sizeof(float), stream);

  hquery_kernel<<<BB, 256, 0, stream>>>(query, W2, b2, hq);
  score_kernel<<<dim3(TT_TOTAL / TTILE, BB), 256, 0, stream>>>(
      values, W1, b1, hq, V, bV, scores);
  softmax_stats_kernel<<<BB, 256, 0, stream>>>(scores, stats);
  context_kernel<<<dim3(TT_TOTAL / TC, BB), 256, 0, stream>>>(
      values, scores, stats, out);
}

// Round 2
// 486.959 us; speedup vs baseline: 1.5458x; 1.5458x over previous
//
#include <hip/hip_runtime.h>
#include <math.h>
#include <stdint.h>

#define BB 32
#define TT 4096
#define DD 512
#define UU 256

#define KC 32        // k-chunk
#define NKC (DD/KC)  // 16
#define LDB 40       // staged row stride in bf16 elems (80 B, 16B-aligned, 20-bank stride)
#define TC 256       // context kernel t rows per block

typedef __attribute__((ext_vector_type(8))) short short8;
typedef __attribute__((ext_vector_type(8))) unsigned short ushort8;
typedef __attribute__((ext_vector_type(4))) float floatx4;

__device__ __forceinline__ unsigned short bf16_rne(float x) {
  union { float f; uint32_t u; } v; v.f = x;
  uint32_t r = v.u + 0x7FFFu + ((v.u >> 16) & 1u);
  return (unsigned short)(r >> 16);
}
__device__ __forceinline__ float tanh_fast(float x) {
  // tanh(x) = 1 - 2/(e^{2x}+1); exp->inf gives 1, exp->0 gives -1 (safe at extremes)
  float e = __expf(2.0f * x);
  return 1.0f - 2.0f * __builtin_amdgcn_rcpf(e + 1.0f);
}

// ---------------------------------------------------------------------------
// Prep: W1 [512][256] fp32 -> staged bf16, transposed + padded, chunk-major:
// staged[(kc*256 + u)*40 + kk] = bf16(W1[kc*32+kk][u]); pad kk=32..39 zeros.
// Score kernel then does a flat 20 KB copy per k-chunk into LDS.
__global__ __launch_bounds__(256) void prep_w1_kernel(
    const float* __restrict__ W1, unsigned short* __restrict__ staged) {
  const int kc = blockIdx.x;   // 0..15
  const int u = threadIdx.x;   // 0..255
  __attribute__((aligned(16))) unsigned short row[LDB];
#pragma unroll
  for (int kk = 0; kk < KC; ++kk)
    row[kk] = bf16_rne(W1[(kc * KC + kk) * UU + u]);  // lanes: consecutive u -> coalesced
#pragma unroll
  for (int kk = KC; kk < LDB; ++kk) row[kk] = 0;
  unsigned short* dst = staged + ((size_t)kc * UU + u) * LDB;
#pragma unroll
  for (int i = 0; i < 5; ++i) ((uint4*)dst)[i] = *(const uint4*)&row[i * 8];
}

// ---------------------------------------------------------------------------
// hq[b][u] = query[b]@W2[:,u] + b2[u] + b1[u]   (b1 folded in for score epilogue)
__global__ __launch_bounds__(256) void hquery_kernel(
    const float* __restrict__ query, const float* __restrict__ W2,
    const float* __restrict__ b2, const float* __restrict__ b1,
    float* __restrict__ hq) {
  const int b = blockIdx.x;
  const int u = threadIdx.x;
  __shared__ float q[DD];
  for (int d = threadIdx.x; d < DD; d += 256) q[d] = query[b * DD + d];
  __syncthreads();
  float acc = b2[u] + b1[u];
  for (int d = 0; d < DD; ++d) acc += q[d] * W2[d * UU + u];
  hq[b * UU + u] = acc;
}

// ---------------------------------------------------------------------------
// scores[b,t] = sum_u tanh( values[b,t,:]@W1[:,u] + hq[b,u] ) * V[u] + bV
// Block: 64 t x 256 u, 4 waves; wave w: t 0..63 x u [w*64, w*64+64).
// mfma_f32_16x16x32_bf16, per wave 4x4 tiles, K-chunks of 32.
__global__ __launch_bounds__(256) void score_kernel(
    const float* __restrict__ values, const unsigned short* __restrict__ w1s,
    const float* __restrict__ hq, const float* __restrict__ V,
    const float* __restrict__ bV, float* __restrict__ scores) {
  const int b = blockIdx.y;
  const int t0 = blockIdx.x * 64;
  const int tid = threadIdx.x;
  const int wave = tid >> 6;
  const int lane = tid & 63;
  const int c = lane & 15;   // mfma col (u within tile) / A row sel
  const int q = lane >> 4;   // quad: k-phase q*8

  __shared__ unsigned short As[64 * LDB];   // values tile bf16 [t][k], stride 40
  __shared__ unsigned short Bs[UU * LDB];   // W1 chunk bf16 [u][k], stride 40
  __shared__ float red[64][17];             // score partials [t][col]

  for (int i = tid; i < 64 * 17; i += 256) ((float*)red)[i] = 0.0f;

  floatx4 acc[4][4];
#pragma unroll
  for (int ti = 0; ti < 4; ++ti)
#pragma unroll
    for (int ui = 0; ui < 4; ++ui) acc[ti][ui] = (floatx4){0.f, 0.f, 0.f, 0.f};

  const size_t vbase = ((size_t)b * TT + t0) * DD;
  const int ar = tid >> 2;   // A-stage row 0..63
  const int aseg = tid & 3;  // 8-float segment within chunk

  for (int kc = 0; kc < NKC; ++kc) {
    __syncthreads();  // red-zero visibility (kc=0) / prior frag reads done
    // --- stage A: 64 rows x 32 d fp32 -> bf16 LDS
    {
      const float* src = values + vbase + (size_t)ar * DD + kc * KC + aseg * 8;
      const float4 f0 = *(const float4*)src;
      const float4 f1 = *(const float4*)(src + 4);
      ushort8 t8;
      t8[0] = bf16_rne(f0.x); t8[1] = bf16_rne(f0.y);
      t8[2] = bf16_rne(f0.z); t8[3] = bf16_rne(f0.w);
      t8[4] = bf16_rne(f1.x); t8[5] = bf16_rne(f1.y);
      t8[6] = bf16_rne(f1.z); t8[7] = bf16_rne(f1.w);
      *(ushort8*)&As[ar * LDB + aseg * 8] = t8;
    }
    // --- stage B: flat 20480 B copy of prestaged chunk
    {
      const uint4* src = (const uint4*)(w1s + (size_t)kc * UU * LDB);
      uint4* dst = (uint4*)Bs;
#pragma unroll
      for (int i = 0; i < 5; ++i) dst[i * 256 + tid] = src[i * 256 + tid];
    }
    __syncthreads();
    // --- fragments (verified layouts: A[m=lane&15][k=q*8+j], B[k=q*8+j][n=lane&15])
    short8 afr[4], bfr[4];
#pragma unroll
    for (int ti = 0; ti < 4; ++ti)
      afr[ti] = *(const short8*)&As[(ti * 16 + c) * LDB + q * 8];
#pragma unroll
    for (int ui = 0; ui < 4; ++ui)
      bfr[ui] = *(const short8*)&Bs[(wave * 64 + ui * 16 + c) * LDB + q * 8];
#pragma unroll
    for (int ti = 0; ti < 4; ++ti)
#pragma unroll
      for (int ui = 0; ui < 4; ++ui)
        acc[ti][ui] = __builtin_amdgcn_mfma_f32_16x16x32_bf16(
            afr[ti], bfr[ui], acc[ti][ui], 0, 0, 0);
  }

  // --- epilogue: e = tanh(h + hq[u]) * V[u], reduce over u into red[t][c]
  float hqv[4], vv[4];
#pragma unroll
  for (int ui = 0; ui < 4; ++ui) {
    const int u = wave * 64 + ui * 16 + c;
    hqv[ui] = hq[b * UU + u];
    vv[ui] = V[u];
  }
#pragma unroll
  for (int ti = 0; ti < 4; ++ti)
#pragma unroll
    for (int r = 0; r < 4; ++r) {
      // C/D layout (verified): row = q*4 + reg, col = lane&15
      const int t = ti * 16 + q * 4 + r;
      float e = 0.0f;
#pragma unroll
      for (int ui = 0; ui < 4; ++ui)
        e += tanh_fast(acc[ti][ui][r] + hqv[ui]) * vv[ui];
      atomicAdd(&red[t][c], e);
    }
  __syncthreads();
  if (tid < 64) {
    float s = bV[0];
#pragma unroll
    for (int x = 0; x < 16; ++x) s += red[tid][x];
    scores[b * TT + t0 + tid] = s;
  }
}

// ---------------------------------------------------------------------------
// per-b softmax stats (max m, sum l)
__global__ __launch_bounds__(256) void softmax_stats_kernel(
    const float* __restrict__ scores, float* __restrict__ stats) {
  const int b = blockIdx.x;
  const int tid = threadIdx.x;
  __shared__ float sm[256];
  float m = -1e30f;
  for (int t = tid; t < TT; t += 256) m = fmaxf(m, scores[b * TT + t]);
  sm[tid] = m;
  __syncthreads();
  for (int s = 128; s > 0; s >>= 1) {
    if (tid < s) sm[tid] = fmaxf(sm[tid], sm[tid + s]);
    __syncthreads();
  }
  m = sm[0];
  __syncthreads();
  float l = 0.0f;
  for (int t = tid; t < TT; t += 256) l += __expf(scores[b * TT + t] - m);
  sm[tid] = l;
  __syncthreads();
  for (int s = 128; s > 0; s >>= 1) {
    if (tid < s) sm[tid] += sm[tid + s];
    __syncthreads();
  }
  if (tid == 0) {
    stats[2 * b] = m;
    stats[2 * b + 1] = sm[0];
  }
}

// ---------------------------------------------------------------------------
// weights out + context partial sums (float4 streaming, atomic accumulate)
__global__ __launch_bounds__(256) void context_kernel(
    const float* __restrict__ values, const float* __restrict__ scores,
    const float* __restrict__ stats, float* __restrict__ out) {
  const int b = blockIdx.y;
  const int tc0 = blockIdx.x * TC;
  const int tid = threadIdx.x;
  const float m = stats[2 * b];
  const float linv = 1.0f / stats[2 * b + 1];

  __shared__ float wts[TC];
  {
    const float w = __expf(scores[b * TT + tc0 + tid] - m) * linv;
    wts[tid] = w;
    out[BB * DD + b * TT + tc0 + tid] = w;  // attention_weights
  }
  __syncthreads();

  const int sub = tid >> 7;   // 0/1: even/odd t rows
  const int d4 = tid & 127;   // float4 index within row
  const float4* vp = (const float4*)(values + ((size_t)b * TT + tc0) * DD);
  float4 acc = {0.f, 0.f, 0.f, 0.f};
#pragma unroll 4
  for (int t = sub; t < TC; t += 2) {
    const float w = wts[t];
    const float4 v = vp[(size_t)t * (DD / 4) + d4];
    acc.x += w * v.x; acc.y += w * v.y; acc.z += w * v.z; acc.w += w * v.w;
  }
  float* o = out + b * DD + d4 * 4;
  atomicAdd(o + 0, acc.x);
  atomicAdd(o + 1, acc.y);
  atomicAdd(o + 2, acc.z);
  atomicAdd(o + 3, acc.w);
}

// ---------------------------------------------------------------------------
extern "C" void kernel_launch(void* const* d_in, const int* in_sizes, int n_in,
                              void* d_out, int out_size, void* d_ws, size_t ws_size,
                              hipStream_t stream) {
  const float* values = (const float*)d_in[0];
  const float* query  = (const float*)d_in[1];
  const float* W1     = (const float*)d_in[2];
  const float* b1     = (const float*)d_in[3];
  const float* W2     = (const float*)d_in[4];
  const float* b2     = (const float*)d_in[5];
  const float* V      = (const float*)d_in[6];
  const float* bV     = (const float*)d_in[7];
  float* out = (float*)d_out;

  float* ws = (float*)d_ws;
  float* hq     = ws;                          // 32*256   = 8192 floats
  float* scores = ws + BB * UU;                // 32*4096  = 131072 floats
  float* stats  = scores + BB * TT;            // 64 floats
  unsigned short* w1s = (unsigned short*)(stats + 2 * BB);  // 16*256*40 bf16 = 320 KB

  // zero the context accumulation region (harness poisons d_out with 0xAA)
  hipMemsetAsync(out, 0, BB * DD * sizeof(float), stream);

  prep_w1_kernel<<<NKC, 256, 0, stream>>>(W1, w1s);
  hquery_kernel<<<BB, 256, 0, stream>>>(query, W2, b2, b1, hq);
  score_kernel<<<dim3(TT / 64, BB), 256, 0, stream>>>(values, w1s, hq, V, bV, scores);
  softmax_stats_kernel<<<BB, 256, 0, stream>>>(scores, stats);
  context_kernel<<<dim3(TT / TC, BB), 256, 0, stream>>>(values, scores, stats, out);
}

// Round 3
// 463.963 us; speedup vs baseline: 1.6224x; 1.0496x over previous
//
#include <hip/hip_runtime.h>
#include <math.h>
#include <stdint.h>

#define BB 32
#define TT 4096
#define DD 512
#define UU 256

#define KC 32        // k-chunk
#define NKC (DD/KC)  // 16
#define LDB 40       // staged row stride in bf16 elems (80 B, 16B-aligned, 20-bank stride)
#define TC 256       // context kernel t rows per block

typedef __attribute__((ext_vector_type(8))) short short8;
typedef __attribute__((ext_vector_type(8))) unsigned short ushort8;
typedef __attribute__((ext_vector_type(4))) float floatx4;

typedef const __attribute__((address_space(1))) unsigned int GU32;
typedef __attribute__((address_space(3))) unsigned int LU32;

__device__ __forceinline__ unsigned short bf16_rne(float x) {
  union { float f; uint32_t u; } v; v.f = x;
  uint32_t r = v.u + 0x7FFFu + ((v.u >> 16) & 1u);
  return (unsigned short)(r >> 16);
}
__device__ __forceinline__ float tanh_fast(float x) {
  // tanh(x) = 1 - 2/(e^{2x}+1); safe at extremes (exp->inf => 1, exp->0 => -1)
  float e = __expf(2.0f * x);
  return 1.0f - 2.0f * __builtin_amdgcn_rcpf(e + 1.0f);
}

// ---------------------------------------------------------------------------
// Prep: W1 [512][256] fp32 -> bf16, transposed + padded, chunk-major:
// staged[(kc*256 + u)*40 + kk] = bf16(W1[kc*32+kk][u]); kk=32..39 zero pad.
__global__ __launch_bounds__(256) void prep_w1_kernel(
    const float* __restrict__ W1, unsigned short* __restrict__ staged) {
  const int kc = blockIdx.x;   // 0..15
  const int u = threadIdx.x;   // 0..255
  __attribute__((aligned(16))) unsigned short row[LDB];
#pragma unroll
  for (int kk = 0; kk < KC; ++kk)
    row[kk] = bf16_rne(W1[(kc * KC + kk) * UU + u]);
#pragma unroll
  for (int kk = KC; kk < LDB; ++kk) row[kk] = 0;
  unsigned short* dst = staged + ((size_t)kc * UU + u) * LDB;
#pragma unroll
  for (int i = 0; i < 5; ++i) ((uint4*)dst)[i] = *(const uint4*)&row[i * 8];
}

// ---------------------------------------------------------------------------
// hq[b][u] = query[b]@W2[:,u] + b2[u] + b1[u]
__global__ __launch_bounds__(256) void hquery_kernel(
    const float* __restrict__ query, const float* __restrict__ W2,
    const float* __restrict__ b2, const float* __restrict__ b1,
    float* __restrict__ hq) {
  const int b = blockIdx.x;
  const int u = threadIdx.x;
  __shared__ float qs[DD];
  for (int d = threadIdx.x; d < DD; d += 256) qs[d] = query[b * DD + d];
  __syncthreads();
  float acc = b2[u] + b1[u];
  for (int d = 0; d < DD; ++d) acc += qs[d] * W2[d * UU + u];
  hq[b * UU + u] = acc;
}

// ---------------------------------------------------------------------------
// scores[b,t] = sum_u tanh( values[b,t,:]@W1[:,u] + hq[b,u] ) * V[u] + bV
// Block: 64 t x 256 u, 4 waves; wave w covers u [w*64, w*64+64), 4x4 mfma tiles.
// B staged via global_load_lds DMA; A prefetched one chunk ahead in registers.
__global__ __launch_bounds__(256) void score_kernel(
    const float* __restrict__ values, const unsigned short* __restrict__ w1s,
    const float* __restrict__ hq, const float* __restrict__ V,
    const float* __restrict__ bV, float* __restrict__ scores) {
  const int b = blockIdx.y;
  const int t0 = blockIdx.x * 64;
  const int tid = threadIdx.x;
  const int wave = tid >> 6;
  const int lane = tid & 63;
  const int c = lane & 15;   // mfma col / A-row select
  const int q = lane >> 4;   // quad: k-phase q*8, C-rows q*4..q*4+3

  __shared__ unsigned short As[64 * LDB];   // values tile bf16 [t][k]
  __shared__ unsigned short Bs[UU * LDB];   // W1 chunk bf16 [u][k]
  __shared__ float redW[4][64];             // per-wave score partials

  floatx4 acc[4][4];
#pragma unroll
  for (int ti = 0; ti < 4; ++ti)
#pragma unroll
    for (int ui = 0; ui < 4; ++ui) acc[ti][ui] = (floatx4){0.f, 0.f, 0.f, 0.f};

  const int ar = tid >> 2;   // A-stage row 0..63
  const int aseg = tid & 3;  // 8-float segment
  const float* asrc =
      values + ((size_t)b * TT + t0) * DD + (size_t)ar * DD + aseg * 8;

  // prefetch chunk 0
  float4 a0 = *(const float4*)asrc;
  float4 a1 = *(const float4*)(asrc + 4);

  for (int kc = 0; kc < NKC; ++kc) {
    __syncthreads();  // prev-iter frag reads done; drains a0/a1 prefetch
    {
      ushort8 t8;
      t8[0] = bf16_rne(a0.x); t8[1] = bf16_rne(a0.y);
      t8[2] = bf16_rne(a0.z); t8[3] = bf16_rne(a0.w);
      t8[4] = bf16_rne(a1.x); t8[5] = bf16_rne(a1.y);
      t8[6] = bf16_rne(a1.z); t8[7] = bf16_rne(a1.w);
      *(ushort8*)&As[ar * LDB + aseg * 8] = t8;
    }
    // B chunk: 20480 B flat DMA global->LDS, 16 B/lane, 5 issues/thread
    {
      GU32* src = (GU32*)(w1s + (size_t)kc * UU * LDB);
      LU32* dst = (LU32*)Bs;
#pragma unroll
      for (int i = 0; i < 5; ++i)
        __builtin_amdgcn_global_load_lds(src + (i * 256 + tid) * 4,
                                         dst + (i * 256 + tid) * 4, 16, 0, 0);
    }
    __syncthreads();  // drains B DMA (vmcnt) + A ds_writes (lgkm)

    short8 afr[4], bfr[4];
#pragma unroll
    for (int ti = 0; ti < 4; ++ti)
      afr[ti] = *(const short8*)&As[(ti * 16 + c) * LDB + q * 8];
#pragma unroll
    for (int ui = 0; ui < 4; ++ui)
      bfr[ui] = *(const short8*)&Bs[(wave * 64 + ui * 16 + c) * LDB + q * 8];
#pragma unroll
    for (int ti = 0; ti < 4; ++ti)
#pragma unroll
      for (int ui = 0; ui < 4; ++ui)
        acc[ti][ui] = __builtin_amdgcn_mfma_f32_16x16x32_bf16(
            afr[ti], bfr[ui], acc[ti][ui], 0, 0, 0);

    // prefetch next A chunk during/after MFMA phase (drained at next barrier)
    if (kc + 1 < NKC) {
      a0 = *(const float4*)(asrc + (kc + 1) * KC);
      a1 = *(const float4*)(asrc + (kc + 1) * KC + 4);
    }
  }

  // epilogue: e = tanh(h + hq[u]) * V[u]; butterfly-reduce over 16-lane c-group
  float hqv[4], vv[4];
#pragma unroll
  for (int ui = 0; ui < 4; ++ui) {
    const int u = wave * 64 + ui * 16 + c;
    hqv[ui] = hq[b * UU + u];
    vv[ui] = V[u];
  }
#pragma unroll
  for (int ti = 0; ti < 4; ++ti)
#pragma unroll
    for (int r = 0; r < 4; ++r) {
      float e = 0.0f;
#pragma unroll
      for (int ui = 0; ui < 4; ++ui)
        e += tanh_fast(acc[ti][ui][r] + hqv[ui]) * vv[ui];
      e += __shfl_xor(e, 1, 64);
      e += __shfl_xor(e, 2, 64);
      e += __shfl_xor(e, 4, 64);
      e += __shfl_xor(e, 8, 64);
      if (c == 0) redW[wave][ti * 16 + q * 4 + r] = e;
    }
  __syncthreads();
  if (tid < 64) {
    const float s =
        bV[0] + redW[0][tid] + redW[1][tid] + redW[2][tid] + redW[3][tid];
    scores[b * TT + t0 + tid] = s;
  }
}

// ---------------------------------------------------------------------------
// per-b softmax stats (max m, sum l)
__global__ __launch_bounds__(256) void softmax_stats_kernel(
    const float* __restrict__ scores, float* __restrict__ stats) {
  const int b = blockIdx.x;
  const int tid = threadIdx.x;
  __shared__ float sm[256];
  float m = -1e30f;
  for (int t = tid; t < TT; t += 256) m = fmaxf(m, scores[b * TT + t]);
  sm[tid] = m;
  __syncthreads();
  for (int s = 128; s > 0; s >>= 1) {
    if (tid < s) sm[tid] = fmaxf(sm[tid], sm[tid + s]);
    __syncthreads();
  }
  m = sm[0];
  __syncthreads();
  float l = 0.0f;
  for (int t = tid; t < TT; t += 256) l += __expf(scores[b * TT + t] - m);
  sm[tid] = l;
  __syncthreads();
  for (int s = 128; s > 0; s >>= 1) {
    if (tid < s) sm[tid] += sm[tid + s];
    __syncthreads();
  }
  if (tid == 0) {
    stats[2 * b] = m;
    stats[2 * b + 1] = sm[0];
  }
}

// ---------------------------------------------------------------------------
// weights out + context partial sums (float4 streaming, atomic accumulate)
__global__ __launch_bounds__(256) void context_kernel(
    const float* __restrict__ values, const float* __restrict__ scores,
    const float* __restrict__ stats, float* __restrict__ out) {
  const int b = blockIdx.y;
  const int tc0 = blockIdx.x * TC;
  const int tid = threadIdx.x;
  const float m = stats[2 * b];
  const float linv = 1.0f / stats[2 * b + 1];

  __shared__ float wts[TC];
  {
    const float w = __expf(scores[b * TT + tc0 + tid] - m) * linv;
    wts[tid] = w;
    out[BB * DD + b * TT + tc0 + tid] = w;  // attention_weights
  }
  __syncthreads();

  const int sub = tid >> 7;   // 0/1: even/odd t rows
  const int d4 = tid & 127;   // float4 index within row
  const float4* vp = (const float4*)(values + ((size_t)b * TT + tc0) * DD);
  float4 acc = {0.f, 0.f, 0.f, 0.f};
#pragma unroll 4
  for (int t = sub; t < TC; t += 2) {
    const float w = wts[t];
    const float4 v = vp[(size_t)t * (DD / 4) + d4];
    acc.x += w * v.x; acc.y += w * v.y; acc.z += w * v.z; acc.w += w * v.w;
  }
  float* o = out + b * DD + d4 * 4;
  atomicAdd(o + 0, acc.x);
  atomicAdd(o + 1, acc.y);
  atomicAdd(o + 2, acc.z);
  atomicAdd(o + 3, acc.w);
}

// ---------------------------------------------------------------------------
extern "C" void kernel_launch(void* const* d_in, const int* in_sizes, int n_in,
                              void* d_out, int out_size, void* d_ws, size_t ws_size,
                              hipStream_t stream) {
  const float* values = (const float*)d_in[0];
  const float* query  = (const float*)d_in[1];
  const float* W1     = (const float*)d_in[2];
  const float* b1     = (const float*)d_in[3];
  const float* W2     = (const float*)d_in[4];
  const float* b2     = (const float*)d_in[5];
  const float* V      = (const float*)d_in[6];
  const float* bV     = (const float*)d_in[7];
  float* out = (float*)d_out;

  float* ws = (float*)d_ws;
  float* hq     = ws;                          // 32*256 floats
  float* scores = ws + BB * UU;                // 32*4096 floats
  float* stats  = scores + BB * TT;            // 64 floats
  unsigned short* w1s = (unsigned short*)(stats + 2 * BB);  // 16*256*40 bf16

  // zero the context accumulation region (harness poisons d_out with 0xAA)
  hipMemsetAsync(out, 0, BB * DD * sizeof(float), stream);

  prep_w1_kernel<<<NKC, 256, 0, stream>>>(W1, w1s);
  hquery_kernel<<<BB, 256, 0, stream>>>(query, W2, b2, b1, hq);
  score_kernel<<<dim3(TT / 64, BB), 256, 0, stream>>>(values, w1s, hq, V, bV, scores);
  softmax_stats_kernel<<<BB, 256, 0, stream>>>(scores, stats);
  context_kernel<<<dim3(TT / TC, BB), 256, 0, stream>>>(values, scores, stats, out);
}

// Round 4
// 461.651 us; speedup vs baseline: 1.6306x; 1.0050x over previous
//
#include <hip/hip_runtime.h>
#include <math.h>
#include <stdint.h>

#define BB 32
#define TT 4096
#define DD 512
#define UU 256

#define KC 32        // k-chunk
#define NKC (DD/KC)  // 16
#define LDB 40       // staged row stride in bf16 elems (80 B, 16B-aligned)
#define NTILE (TT/64)  // 64 t-tiles per batch

typedef __attribute__((ext_vector_type(8))) short short8;
typedef __attribute__((ext_vector_type(8))) unsigned short ushort8;
typedef __attribute__((ext_vector_type(4))) float floatx4;

typedef const __attribute__((address_space(1))) unsigned int GU32;
typedef __attribute__((address_space(3))) unsigned int LU32;

__device__ __forceinline__ unsigned short bf16_rne(float x) {
  union { float f; uint32_t u; } v; v.f = x;
  uint32_t r = v.u + 0x7FFFu + ((v.u >> 16) & 1u);
  return (unsigned short)(r >> 16);
}
__device__ __forceinline__ float tanh_fast(float x) {
  // tanh(x) = 1 - 2/(e^{2x}+1); safe at extremes (exp->inf => 1, exp->0 => -1)
  float e = __expf(2.0f * x);
  return 1.0f - 2.0f * __builtin_amdgcn_rcpf(e + 1.0f);
}

// ---------------------------------------------------------------------------
// Prep: W1 [512][256] fp32 -> bf16, transposed + padded, chunk-major:
// staged[(kc*256 + u)*40 + kk] = bf16(W1[kc*32+kk][u]); kk=32..39 zero pad.
__global__ __launch_bounds__(256) void prep_w1_kernel(
    const float* __restrict__ W1, unsigned short* __restrict__ staged) {
  const int kc = blockIdx.x;   // 0..15
  const int u = threadIdx.x;   // 0..255
  __attribute__((aligned(16))) unsigned short row[LDB];
#pragma unroll
  for (int kk = 0; kk < KC; ++kk)
    row[kk] = bf16_rne(W1[(kc * KC + kk) * UU + u]);
#pragma unroll
  for (int kk = KC; kk < LDB; ++kk) row[kk] = 0;
  unsigned short* dst = staged + ((size_t)kc * UU + u) * LDB;
#pragma unroll
  for (int i = 0; i < 5; ++i) ((uint4*)dst)[i] = *(const uint4*)&row[i * 8];
}

// ---------------------------------------------------------------------------
// hq[b][u] = query[b]@W2[:,u] + b2[u] + b1[u]
__global__ __launch_bounds__(256) void hquery_kernel(
    const float* __restrict__ query, const float* __restrict__ W2,
    const float* __restrict__ b2, const float* __restrict__ b1,
    float* __restrict__ hq) {
  const int b = blockIdx.x;
  const int u = threadIdx.x;
  __shared__ float qs[DD];
  for (int d = threadIdx.x; d < DD; d += 256) qs[d] = query[b * DD + d];
  __syncthreads();
  float acc = b2[u] + b1[u];
  for (int d = 0; d < DD; ++d) acc += qs[d] * W2[d * UU + u];
  hq[b * UU + u] = acc;
}

// ---------------------------------------------------------------------------
// Fused: scores[b,t] (raw, for weights kernel) + block-local softmax partials:
//   m_b, l_b, pctx_b[512] = sum_t exp(s_t - m_b) * values[b,t,:]
// Block: 64 t x 256 u, 4 waves, 4x4 mfma_f32_16x16x32_bf16 tiles per wave.
__global__ __launch_bounds__(256) void score_kernel(
    const float* __restrict__ values, const unsigned short* __restrict__ w1s,
    const float* __restrict__ hq, const float* __restrict__ V,
    const float* __restrict__ bV, float* __restrict__ scores,
    float* __restrict__ pml, float* __restrict__ pctx) {
  const int b = blockIdx.y;
  const int blk = blockIdx.x;
  const int t0 = blk * 64;
  const int tid = threadIdx.x;
  const int wave = tid >> 6;
  const int lane = tid & 63;
  const int c = lane & 15;   // mfma col / A-row select
  const int q = lane >> 4;   // quad: k-phase q*8, C-rows q*4..q*4+3

  __shared__ unsigned short As[64 * LDB];   // values tile bf16 [t][k]
  __shared__ unsigned short Bs[UU * LDB];   // W1 chunk bf16 [u][k]
  __shared__ float redW[4][64];             // per-wave score partials
  __shared__ float warr[64];                // softmax weights (block-local)

  floatx4 acc[4][4];
#pragma unroll
  for (int ti = 0; ti < 4; ++ti)
#pragma unroll
    for (int ui = 0; ui < 4; ++ui) acc[ti][ui] = (floatx4){0.f, 0.f, 0.f, 0.f};

  const int ar = tid >> 2;   // A-stage row 0..63
  const int aseg = tid & 3;  // 8-float segment
  const float* asrc =
      values + ((size_t)b * TT + t0) * DD + (size_t)ar * DD + aseg * 8;

  // prefetch chunk 0
  float4 a0 = *(const float4*)asrc;
  float4 a1 = *(const float4*)(asrc + 4);

  for (int kc = 0; kc < NKC; ++kc) {
    __syncthreads();  // prev-iter frag reads done; a0/a1 prefetch drained
    {
      ushort8 t8;
      t8[0] = bf16_rne(a0.x); t8[1] = bf16_rne(a0.y);
      t8[2] = bf16_rne(a0.z); t8[3] = bf16_rne(a0.w);
      t8[4] = bf16_rne(a1.x); t8[5] = bf16_rne(a1.y);
      t8[6] = bf16_rne(a1.z); t8[7] = bf16_rne(a1.w);
      *(ushort8*)&As[ar * LDB + aseg * 8] = t8;
    }
    // B chunk: 20480 B flat DMA global->LDS, 16 B/lane
    {
      GU32* src = (GU32*)(w1s + (size_t)kc * UU * LDB);
      LU32* dst = (LU32*)Bs;
#pragma unroll
      for (int i = 0; i < 5; ++i)
        __builtin_amdgcn_global_load_lds(src + (i * 256 + tid) * 4,
                                         dst + (i * 256 + tid) * 4, 16, 0, 0);
    }
    __syncthreads();  // drains B DMA (vmcnt) + A ds_writes (lgkm)

    short8 afr[4], bfr[4];
#pragma unroll
    for (int ti = 0; ti < 4; ++ti)
      afr[ti] = *(const short8*)&As[(ti * 16 + c) * LDB + q * 8];
#pragma unroll
    for (int ui = 0; ui < 4; ++ui)
      bfr[ui] = *(const short8*)&Bs[(wave * 64 + ui * 16 + c) * LDB + q * 8];
#pragma unroll
    for (int ti = 0; ti < 4; ++ti)
#pragma unroll
      for (int ui = 0; ui < 4; ++ui)
        acc[ti][ui] = __builtin_amdgcn_mfma_f32_16x16x32_bf16(
            afr[ti], bfr[ui], acc[ti][ui], 0, 0, 0);

    if (kc + 1 < NKC) {
      a0 = *(const float4*)(asrc + (kc + 1) * KC);
      a1 = *(const float4*)(asrc + (kc + 1) * KC + 4);
    }
  }

  // epilogue: e = tanh(h + hq[u]) * V[u]; butterfly over 16-lane c-group
  float hqv[4], vv[4];
#pragma unroll
  for (int ui = 0; ui < 4; ++ui) {
    const int u = wave * 64 + ui * 16 + c;
    hqv[ui] = hq[b * UU + u];
    vv[ui] = V[u];
  }
#pragma unroll
  for (int ti = 0; ti < 4; ++ti)
#pragma unroll
    for (int r = 0; r < 4; ++r) {
      float e = 0.0f;
#pragma unroll
      for (int ui = 0; ui < 4; ++ui)
        e += tanh_fast(acc[ti][ui][r] + hqv[ui]) * vv[ui];
      e += __shfl_xor(e, 1, 64);
      e += __shfl_xor(e, 2, 64);
      e += __shfl_xor(e, 4, 64);
      e += __shfl_xor(e, 8, 64);
      if (c == 0) redW[wave][ti * 16 + q * 4 + r] = e;
    }
  __syncthreads();
  // final scores into redW[0][t] (reused as sarr)
  if (tid < 64) {
    const float s =
        bV[0] + redW[0][tid] + redW[1][tid] + redW[2][tid] + redW[3][tid];
    scores[b * TT + t0 + tid] = s;
    redW[0][tid] = s;
  }
  __syncthreads();
  // block-local max (redundant broadcast reads, no conflicts)
  float mb = -1e30f;
#pragma unroll 8
  for (int t = 0; t < 64; ++t) mb = fmaxf(mb, redW[0][t]);
  if (tid < 64) warr[tid] = __expf(redW[0][tid] - mb);
  __syncthreads();
  float lb = 0.0f;
#pragma unroll 8
  for (int t = 0; t < 64; ++t) lb += warr[t];

  // partial context: thread owns float2 at d = 2*tid; values tile is L2-hot
  const float2* vp = (const float2*)(values + ((size_t)b * TT + t0) * DD);
  float2 c2 = {0.f, 0.f};
#pragma unroll 4
  for (int t = 0; t < 64; ++t) {
    const float w = warr[t];
    const float2 v = vp[(size_t)t * (DD / 2) + tid];
    c2.x += w * v.x;
    c2.y += w * v.y;
  }
  *(float2*)&pctx[((size_t)b * NTILE + blk) * DD + 2 * tid] = c2;
  if (tid == 0) {
    pml[(b * NTILE + blk) * 2 + 0] = mb;
    pml[(b * NTILE + blk) * 2 + 1] = lb;
  }
}

// ---------------------------------------------------------------------------
// Combine: per b, global m/l from 64 tile-partials, rescale+sum pctx -> out.
__global__ __launch_bounds__(256) void combine_kernel(
    const float* __restrict__ pml, const float* __restrict__ pctx,
    float* __restrict__ out, float* __restrict__ stats) {
  const int b = blockIdx.x;
  const int tid = threadIdx.x;
  __shared__ float mls[2 * NTILE];
  __shared__ float cs[NTILE];
  if (tid < 2 * NTILE) mls[tid] = pml[b * 2 * NTILE + tid];
  __syncthreads();
  float m = -1e30f;
#pragma unroll 8
  for (int i = 0; i < NTILE; ++i) m = fmaxf(m, mls[2 * i]);
  if (tid < NTILE) cs[tid] = __expf(mls[2 * tid] - m);
  __syncthreads();
  float l = 0.0f;
#pragma unroll 8
  for (int i = 0; i < NTILE; ++i) l += cs[i] * mls[2 * i + 1];

  const float2* pp = (const float2*)(pctx + (size_t)b * NTILE * DD);
  float2 acc = {0.f, 0.f};
#pragma unroll 4
  for (int i = 0; i < NTILE; ++i) {
    const float cw = cs[i];
    const float2 p = pp[(size_t)i * (DD / 2) + tid];
    acc.x += cw * p.x;
    acc.y += cw * p.y;
  }
  const float linv = 1.0f / l;
  out[b * DD + 2 * tid + 0] = acc.x * linv;
  out[b * DD + 2 * tid + 1] = acc.y * linv;
  if (tid == 0) {
    stats[2 * b + 0] = m;
    stats[2 * b + 1] = l;
  }
}

// ---------------------------------------------------------------------------
// weights[b,t] = exp(scores[b,t] - m) / l
__global__ __launch_bounds__(256) void weights_kernel(
    const float* __restrict__ scores, const float* __restrict__ stats,
    float* __restrict__ out) {
  const int b = blockIdx.y;
  const int t = blockIdx.x * 256 + threadIdx.x;
  const float m = stats[2 * b];
  const float linv = 1.0f / stats[2 * b + 1];
  out[BB * DD + b * TT + t] = __expf(scores[b * TT + t] - m) * linv;
}

// ---------------------------------------------------------------------------
extern "C" void kernel_launch(void* const* d_in, const int* in_sizes, int n_in,
                              void* d_out, int out_size, void* d_ws, size_t ws_size,
                              hipStream_t stream) {
  const float* values = (const float*)d_in[0];
  const float* query  = (const float*)d_in[1];
  const float* W1     = (const float*)d_in[2];
  const float* b1     = (const float*)d_in[3];
  const float* W2     = (const float*)d_in[4];
  const float* b2     = (const float*)d_in[5];
  const float* V      = (const float*)d_in[6];
  const float* bV     = (const float*)d_in[7];
  float* out = (float*)d_out;

  float* ws = (float*)d_ws;
  float* hq     = ws;                          // 32*256 floats
  float* scores = ws + BB * UU;                // 32*4096 floats
  float* stats  = scores + BB * TT;            // 64 floats
  float* pml    = stats + 2 * BB;              // 32*64*2 = 4096 floats
  float* pctx   = pml + BB * NTILE * 2;        // 32*64*512 = 1M floats (4 MB)
  unsigned short* w1s = (unsigned short*)(pctx + (size_t)BB * NTILE * DD);

  prep_w1_kernel<<<NKC, 256, 0, stream>>>(W1, w1s);
  hquery_kernel<<<BB, 256, 0, stream>>>(query, W2, b2, b1, hq);
  score_kernel<<<dim3(NTILE, BB), 256, 0, stream>>>(
      values, w1s, hq, V, bV, scores, pml, pctx);
  combine_kernel<<<BB, 256, 0, stream>>>(pml, pctx, out, stats);
  weights_kernel<<<dim3(TT / 256, BB), 256, 0, stream>>>(scores, stats, out);
}

// Round 5
// 456.914 us; speedup vs baseline: 1.6475x; 1.0104x over previous
//
#include <hip/hip_runtime.h>
#include <math.h>
#include <stdint.h>

#define BB 32
#define TT 4096
#define DD 512
#define UU 256

#define KC 32          // k-chunk
#define NKC (DD/KC)    // 16
#define LDA 40         // As row stride in bf16 (80 B: 20-bank stride, 2-way only)
#define NTILE (TT/64)  // 64 t-tiles per batch

typedef __attribute__((ext_vector_type(8))) short short8;
typedef __attribute__((ext_vector_type(8))) unsigned short ushort8;
typedef __attribute__((ext_vector_type(4))) float floatx4;

__device__ __forceinline__ unsigned short bf16_rne(float x) {
  union { float f; uint32_t u; } v; v.f = x;
  uint32_t r = v.u + 0x7FFFu + ((v.u >> 16) & 1u);
  return (unsigned short)(r >> 16);
}
__device__ __forceinline__ float tanh_fast(float x) {
  float e = __expf(2.0f * x);
  return 1.0f - 2.0f * __builtin_amdgcn_rcpf(e + 1.0f);
}

// ---------------------------------------------------------------------------
// Prep: W1 [512][256] fp32 -> bf16 transposed, chunk-major, UNPADDED stride 32:
// w1t[(kc*256 + u)*32 + kk] = bf16(W1[(kc*32+kk)*256 + u])
// Score kernel loads MFMA B-fragments directly from this (16 B/lane, coalesced).
__global__ __launch_bounds__(256) void prep_w1_kernel(
    const float* __restrict__ W1, unsigned short* __restrict__ w1t) {
  const int kc = blockIdx.x;   // 0..15
  const int u = threadIdx.x;   // 0..255
  __attribute__((aligned(16))) unsigned short row[KC];
#pragma unroll
  for (int kk = 0; kk < KC; ++kk)
    row[kk] = bf16_rne(W1[(kc * KC + kk) * UU + u]);
  unsigned short* dst = w1t + ((size_t)kc * UU + u) * KC;
#pragma unroll
  for (int i = 0; i < 4; ++i) ((uint4*)dst)[i] = *(const uint4*)&row[i * 8];
}

// ---------------------------------------------------------------------------
// hq[b][u] = query[b]@W2[:,u] + b2[u] + b1[u]
__global__ __launch_bounds__(256) void hquery_kernel(
    const float* __restrict__ query, const float* __restrict__ W2,
    const float* __restrict__ b2, const float* __restrict__ b1,
    float* __restrict__ hq) {
  const int b = blockIdx.x;
  const int u = threadIdx.x;
  __shared__ float qs[DD];
  for (int d = threadIdx.x; d < DD; d += 256) qs[d] = query[b * DD + d];
  __syncthreads();
  float acc = b2[u] + b1[u];
  for (int d = 0; d < DD; ++d) acc += qs[d] * W2[d * UU + u];
  hq[b * UU + u] = acc;
}

// ---------------------------------------------------------------------------
// Fused: raw scores + block-local softmax partials (m_b, l_b, pctx_b[512]).
// Block: 64 t x 256 u, 4 waves. Single barrier per k-chunk (dbuf A in LDS),
// B-fragments direct from global (L1/L2-hot W1T), A reg-prefetch distance 2.
__global__ __launch_bounds__(256) void score_kernel(
    const float* __restrict__ values, const unsigned short* __restrict__ w1t,
    const float* __restrict__ hq, const float* __restrict__ V,
    const float* __restrict__ bV, float* __restrict__ scores,
    float* __restrict__ pml, float* __restrict__ pctx) {
  const int b = blockIdx.y;
  const int blk = blockIdx.x;
  const int t0 = blk * 64;
  const int tid = threadIdx.x;
  const int wave = tid >> 6;
  const int lane = tid & 63;
  const int c = lane & 15;   // mfma col / A-row select
  const int q = lane >> 4;   // quad: k-phase q*8, C-rows q*4..q*4+3

  __shared__ unsigned short As[2][64 * LDA];  // dbuf values tile bf16 [t][k]
  __shared__ float redW[4][64];               // per-wave score partials
  __shared__ float warr[64];                  // block-local softmax weights

  floatx4 acc[4][4];
#pragma unroll
  for (int ti = 0; ti < 4; ++ti)
#pragma unroll
    for (int ui = 0; ui < 4; ++ui) acc[ti][ui] = (floatx4){0.f, 0.f, 0.f, 0.f};

  const int ar = tid >> 2;   // A-stage row 0..63
  const int aseg = tid & 3;  // 8-float segment
  const float* asrc =
      values + ((size_t)b * TT + t0 + ar) * DD + aseg * 8;

  // B-fragment base for this lane (16 B contiguous per fragment)
  const unsigned short* bbase = w1t + ((size_t)(wave * 64 + c)) * KC + q * 8;

  // A register prefetch, distance 2: aq[p] holds chunk (kc with kc&1==p)
  float4 aq[2][2];
  aq[0][0] = *(const float4*)(asrc);
  aq[0][1] = *(const float4*)(asrc + 4);
  aq[1][0] = *(const float4*)(asrc + KC);
  aq[1][1] = *(const float4*)(asrc + KC + 4);

  for (int kc = 0; kc < NKC; ++kc) {
    const int buf = kc & 1;
    // stage chunk kc from registers into As[buf] (nobody reads As[buf] now)
    {
      const float4 f0 = aq[buf][0], f1 = aq[buf][1];
      ushort8 t8;
      t8[0] = bf16_rne(f0.x); t8[1] = bf16_rne(f0.y);
      t8[2] = bf16_rne(f0.z); t8[3] = bf16_rne(f0.w);
      t8[4] = bf16_rne(f1.x); t8[5] = bf16_rne(f1.y);
      t8[6] = bf16_rne(f1.z); t8[7] = bf16_rne(f1.w);
      *(ushort8*)&As[buf][ar * LDA + aseg * 8] = t8;
    }
    __syncthreads();  // orders A writes before reads; drains prefetches

    // B fragments: direct global (coalesced 1 KB/instr, L1/L2-hot)
    short8 bfr[4];
#pragma unroll
    for (int ui = 0; ui < 4; ++ui)
      bfr[ui] = *(const short8*)(bbase + ((size_t)kc * UU + ui * 16) * KC);
    // A fragments from LDS
    short8 afr[4];
#pragma unroll
    for (int ti = 0; ti < 4; ++ti)
      afr[ti] = *(const short8*)&As[buf][(ti * 16 + c) * LDA + q * 8];

    // prefetch chunk kc+2 into the register slot just staged
    if (kc + 2 < NKC) {
      aq[buf][0] = *(const float4*)(asrc + (kc + 2) * KC);
      aq[buf][1] = *(const float4*)(asrc + (kc + 2) * KC + 4);
    }

#pragma unroll
    for (int ti = 0; ti < 4; ++ti)
#pragma unroll
      for (int ui = 0; ui < 4; ++ui)
        acc[ti][ui] = __builtin_amdgcn_mfma_f32_16x16x32_bf16(
            afr[ti], bfr[ui], acc[ti][ui], 0, 0, 0);
  }

  // epilogue: e = tanh(h + hq[u]) * V[u]; butterfly over 16-lane c-group
  float hqv[4], vv[4];
#pragma unroll
  for (int ui = 0; ui < 4; ++ui) {
    const int u = wave * 64 + ui * 16 + c;
    hqv[ui] = hq[b * UU + u];
    vv[ui] = V[u];
  }
#pragma unroll
  for (int ti = 0; ti < 4; ++ti)
#pragma unroll
    for (int r = 0; r < 4; ++r) {
      float e = 0.0f;
#pragma unroll
      for (int ui = 0; ui < 4; ++ui)
        e += tanh_fast(acc[ti][ui][r] + hqv[ui]) * vv[ui];
      e += __shfl_xor(e, 1, 64);
      e += __shfl_xor(e, 2, 64);
      e += __shfl_xor(e, 4, 64);
      e += __shfl_xor(e, 8, 64);
      if (c == 0) redW[wave][ti * 16 + q * 4 + r] = e;
    }
  __syncthreads();
  if (tid < 64) {
    const float s =
        bV[0] + redW[0][tid] + redW[1][tid] + redW[2][tid] + redW[3][tid];
    scores[b * TT + t0 + tid] = s;
    redW[0][tid] = s;
  }
  __syncthreads();
  float mb = -1e30f;
#pragma unroll 8
  for (int t = 0; t < 64; ++t) mb = fmaxf(mb, redW[0][t]);
  if (tid < 64) warr[tid] = __expf(redW[0][tid] - mb);
  __syncthreads();
  float lb = 0.0f;
#pragma unroll 8
  for (int t = 0; t < 64; ++t) lb += warr[t];

  // partial context: thread owns float2 at d = 2*tid; values tile is L2-hot
  const float2* vp = (const float2*)(values + ((size_t)b * TT + t0) * DD);
  float2 c2 = {0.f, 0.f};
#pragma unroll 4
  for (int t = 0; t < 64; ++t) {
    const float w = warr[t];
    const float2 v = vp[(size_t)t * (DD / 2) + tid];
    c2.x += w * v.x;
    c2.y += w * v.y;
  }
  *(float2*)&pctx[((size_t)b * NTILE + blk) * DD + 2 * tid] = c2;
  if (tid == 0) {
    pml[(b * NTILE + blk) * 2 + 0] = mb;
    pml[(b * NTILE + blk) * 2 + 1] = lb;
  }
}

// ---------------------------------------------------------------------------
// Combine: per b, global m/l from 64 tile-partials, rescale+sum pctx -> out.
__global__ __launch_bounds__(256) void combine_kernel(
    const float* __restrict__ pml, const float* __restrict__ pctx,
    float* __restrict__ out, float* __restrict__ stats) {
  const int b = blockIdx.x;
  const int tid = threadIdx.x;
  __shared__ float mls[2 * NTILE];
  __shared__ float cs[NTILE];
  if (tid < 2 * NTILE) mls[tid] = pml[b * 2 * NTILE + tid];
  __syncthreads();
  float m = -1e30f;
#pragma unroll 8
  for (int i = 0; i < NTILE; ++i) m = fmaxf(m, mls[2 * i]);
  if (tid < NTILE) cs[tid] = __expf(mls[2 * tid] - m);
  __syncthreads();
  float l = 0.0f;
#pragma unroll 8
  for (int i = 0; i < NTILE; ++i) l += cs[i] * mls[2 * i + 1];

  const float2* pp = (const float2*)(pctx + (size_t)b * NTILE * DD);
  float2 acc = {0.f, 0.f};
#pragma unroll 4
  for (int i = 0; i < NTILE; ++i) {
    const float cw = cs[i];
    const float2 p = pp[(size_t)i * (DD / 2) + tid];
    acc.x += cw * p.x;
    acc.y += cw * p.y;
  }
  const float linv = 1.0f / l;
  out[b * DD + 2 * tid + 0] = acc.x * linv;
  out[b * DD + 2 * tid + 1] = acc.y * linv;
  if (tid == 0) {
    stats[2 * b + 0] = m;
    stats[2 * b + 1] = l;
  }
}

// ---------------------------------------------------------------------------
// weights[b,t] = exp(scores[b,t] - m) / l
__global__ __launch_bounds__(256) void weights_kernel(
    const float* __restrict__ scores, const float* __restrict__ stats,
    float* __restrict__ out) {
  const int b = blockIdx.y;
  const int t = blockIdx.x * 256 + threadIdx.x;
  const float m = stats[2 * b];
  const float linv = 1.0f / stats[2 * b + 1];
  out[BB * DD + b * TT + t] = __expf(scores[b * TT + t] - m) * linv;
}

// ---------------------------------------------------------------------------
extern "C" void kernel_launch(void* const* d_in, const int* in_sizes, int n_in,
                              void* d_out, int out_size, void* d_ws, size_t ws_size,
                              hipStream_t stream) {
  const float* values = (const float*)d_in[0];
  const float* query  = (const float*)d_in[1];
  const float* W1     = (const float*)d_in[2];
  const float* b1     = (const float*)d_in[3];
  const float* W2     = (const float*)d_in[4];
  const float* b2     = (const float*)d_in[5];
  const float* V      = (const float*)d_in[6];
  const float* bV     = (const float*)d_in[7];
  float* out = (float*)d_out;

  float* ws = (float*)d_ws;
  float* hq     = ws;                          // 32*256 floats
  float* scores = ws + BB * UU;                // 32*4096 floats
  float* stats  = scores + BB * TT;            // 64 floats
  float* pml    = stats + 2 * BB;              // 32*64*2 = 4096 floats
  float* pctx   = pml + BB * NTILE * 2;        // 32*64*512 floats (4 MB)
  unsigned short* w1t = (unsigned short*)(pctx + (size_t)BB * NTILE * DD);

  prep_w1_kernel<<<NKC, 256, 0, stream>>>(W1, w1t);
  hquery_kernel<<<BB, 256, 0, stream>>>(query, W2, b2, b1, hq);
  score_kernel<<<dim3(NTILE, BB), 256, 0, stream>>>(
      values, w1t, hq, V, bV, scores, pml, pctx);
  combine_kernel<<<BB, 256, 0, stream>>>(pml, pctx, out, stats);
  weights_kernel<<<dim3(TT / 256, BB), 256, 0, stream>>>(scores, stats, out);
}